// Round 9
// baseline (138.299 us; speedup 1.0000x reference)
//
#include <hip/hip_runtime.h>
#include <cstdint>

// ---------------------------------------------------------------------------
// Composer_81707457839189 — mode-per-lane layout (R9).
//   lane = (row, mode): 16 lanes/row, 4 rows/wave, 16 rows/block-iter.
//   modal[i] = sum_j exp2(g_ij*(L_i-L_j) + L_j)   (j==i gives phi_i, 1-ulp)
//   log-softmax over the 16-lane mode groups via shfl_xor reductions.
// History:
//   R5: NO nontemporal stores (2.6x write amplification, 166MB vs 64MB).
//   R7/R8: row-per-thread is latency-bound regardless of occupancy/ILP —
//   VALUBusy*dur ~= 14us constant while dur 43-50us; 274 serial trans
//   chains/thread + per-pair uniform g fetch (LDS or spilled s_load) stall
//   ~70% of cycles. R9 moves pairs across lanes: 16x shorter chains, g in
//   per-lane VGPRs, perfect 4B/lane coalescing.
// ws layout: uint ws[0..255]: column-min c at ws[c*16] (64B line per column);
//            float ws[256..511]: symmetrized G (16x16), built by k_init.
// ---------------------------------------------------------------------------

#define EC    2.71828182845904523536f
#define LOG2E 1.44269504088896340736f
#define LN2   0.69314718055994530942f

typedef float f32x4 __attribute__((ext_vector_type(4)));

__device__ __forceinline__ unsigned int ordmap(float f) {
    unsigned int u = __float_as_uint(f);
    return u ^ ((unsigned int)((int)u >> 31) | 0x80000000u);
}
__device__ __forceinline__ float ordunmap(unsigned int u) {
    unsigned int bits = (u & 0x80000000u) ? (u ^ 0x80000000u) : ~u;
    return __uint_as_float(bits);
}

// Re-poisoned ws every timed launch -> rebuild both wsmin sentinels and G.
__global__ void k_init(unsigned int* __restrict__ ws,
                       const float* __restrict__ gam) {
    int t = threadIdx.x;           // 256 threads
    ws[t] = 0xFFFFFFFFu;           // +inf (ordered map), covers padded slots
    int i = t >> 4, j = t & 15;
    float g = (i < j) ? gam[i * 16 + j]
                      : ((i > j) ? gam[j * 16 + i] : gam[t]);  // diag unused (d=0)
    ((float*)ws)[256 + t] = g;
}

// Per-column min of V (N x 16, row-major) via ordered-uint atomicMin.
__global__ __launch_bounds__(256) void k_colmin(const float4* __restrict__ V4,
                                                unsigned int* __restrict__ ws,
                                                int n4) {
    int tid = blockIdx.x * blockDim.x + threadIdx.x;
    int stride = gridDim.x * blockDim.x;  // multiple of 4
    float4 m = make_float4(__builtin_inff(), __builtin_inff(),
                           __builtin_inff(), __builtin_inff());
    for (int i = tid; i < n4; i += stride) {
        float4 v = V4[i];
        m.x = fminf(m.x, v.x);
        m.y = fminf(m.y, v.y);
        m.z = fminf(m.z, v.z);
        m.w = fminf(m.w, v.w);
    }
    #pragma unroll
    for (int off = 4; off <= 32; off <<= 1) {
        m.x = fminf(m.x, __shfl_xor(m.x, off));
        m.y = fminf(m.y, __shfl_xor(m.y, off));
        m.z = fminf(m.z, __shfl_xor(m.z, off));
        m.w = fminf(m.w, __shfl_xor(m.w, off));
    }
    __shared__ float lmin[4][16];
    int lane = threadIdx.x & 63;
    int wv   = threadIdx.x >> 6;
    if (lane < 4) {
        lmin[wv][lane * 4 + 0] = m.x;
        lmin[wv][lane * 4 + 1] = m.y;
        lmin[wv][lane * 4 + 2] = m.z;
        lmin[wv][lane * 4 + 3] = m.w;
    }
    __syncthreads();
    if (threadIdx.x < 16) {
        float mm = fminf(fminf(lmin[0][threadIdx.x], lmin[1][threadIdx.x]),
                         fminf(lmin[2][threadIdx.x], lmin[3][threadIdx.x]));
        atomicMin(&ws[threadIdx.x * 16], ordmap(mm));
    }
}

__global__ __launch_bounds__(256) void k_main(const float* __restrict__ V,
                                              const float* __restrict__ w,
                                              const float* __restrict__ b,
                                              const unsigned int* __restrict__ ws,
                                              float* __restrict__ out, int N) {
    const int t   = threadIdx.x;
    const int i16 = t & 15;                       // my mode index

    // Per-lane mode constants (vector loads, L2-hot, once per thread).
    const float cw = 1.0f + w[i16];
    const float cb = b[i16];
    const float vm = ordunmap(ws[i16 * 16]);

    // My G row into 16 VGPRs.
    float g[16];
    {
        const f32x4* G4 = (const f32x4*)((const float*)ws + 256);
        #pragma unroll
        for (int q = 0; q < 4; ++q) {
            f32x4 gv = G4[i16 * 4 + q];
            g[q*4+0] = gv[0]; g[q*4+1] = gv[1];
            g[q*4+2] = gv[2]; g[q*4+3] = gv[3];
        }
    }

    __shared__ float sL[256];                     // [16 rows][16 modes]
    f32x4* sL4 = (f32x4*)sL;
    const int rowq = (t >> 4) * 4;                // my row's float4 base in sL

    const size_t NM = (size_t)N * 16;
    const int ngroups = (N + 15) >> 4;            // 31250 for N=500000 (exact)

    for (int grp = blockIdx.x; grp < ngroups; grp += gridDim.x) {
        const size_t base = (size_t)grp * 256 + t;  // flat elem = row*16 + mode
        const bool valid = base < NM;               // whole rows only

        float v   = valid ? V[base] : vm;           // clamp -> phi>0 for log
        float phi = __builtin_fmaf(cw, fmaxf(v - vm + EC, EC), cb);
        float L   = __builtin_amdgcn_logf(phi);     // v_log_f32 (log2)

        // Wave-local transpose: all 16 L of my row into registers.
        // (DS ops are in-order per wave; 16 lanes read identical addresses
        //  -> broadcast, conflict-free; no __syncthreads needed.)
        sL[t] = L;
        float Lv[16];
        #pragma unroll
        for (int q = 0; q < 4; ++q) {
            f32x4 lv = sL4[rowq + q];
            Lv[q*4+0] = lv[0]; Lv[q*4+1] = lv[1];
            Lv[q*4+2] = lv[2]; Lv[q*4+3] = lv[3];
        }

        // modal_i = sum_j exp2(g_j*(L_i - L_j) + L_j); j==i -> exp2(L_i)=phi.
        float modal = 0.0f;
        #pragma unroll
        for (int j = 0; j < 16; ++j) {
            float d = L - Lv[j];
            modal += __builtin_amdgcn_exp2f(__builtin_fmaf(g[j], d, Lv[j]));
        }

        // log-softmax across the 16-lane mode group.
        float x  = -0.25f * modal;                  // tau = 1/sqrt(16)
        float mx = x;
        #pragma unroll
        for (int k = 1; k < 16; k <<= 1)
            mx = fmaxf(mx, __shfl_xor(mx, k));
        float e = __builtin_amdgcn_exp2f((x - mx) * LOG2E);
        float s = e;
        #pragma unroll
        for (int k = 1; k < 16; k <<= 1)
            s += __shfl_xor(s, k);
        float alpha = e * __builtin_amdgcn_rcpf(s);
        float logit = x - mx - __builtin_amdgcn_logf(s) * LN2;

        if (valid) {
            out[base]      = alpha;                 // 4B/lane, coalesced
            out[NM + base] = logit;
        }
    }
}

extern "C" void kernel_launch(void* const* d_in, const int* in_sizes, int n_in,
                              void* d_out, int out_size, void* d_ws, size_t ws_size,
                              hipStream_t stream) {
    (void)n_in; (void)out_size; (void)ws_size;
    const float* V   = (const float*)d_in[0];
    const float* w   = (const float*)d_in[1];
    const float* b   = (const float*)d_in[2];
    const float* gam = (const float*)d_in[3];
    float* out = (float*)d_out;
    unsigned int* wsmin = (unsigned int*)d_ws;

    const int N  = in_sizes[0] / 16;
    const int n4 = N * 4;  // float4 count

    hipLaunchKernelGGL(k_init, dim3(1), dim3(256), 0, stream, wsmin, gam);
    hipLaunchKernelGGL(k_colmin, dim3(1024), dim3(256), 0, stream,
                       (const float4*)V, wsmin, n4);
    hipLaunchKernelGGL(k_main, dim3(2048), dim3(256), 0, stream,
                       V, w, b, wsmin, out, N);
}